// Round 1
// baseline (1162.879 us; speedup 1.0000x reference)
//
#include <hip/hip_runtime.h>
#include <math.h>

#define NIMG 16
#define A_ 3
#define H_ 160
#define W_ 160
#define C_ 80
#define HW_ (H_*W_)        // 25600
#define P_ (HW_*A_)        // 76800
#define K1 4096
#define K2 300
#define CAND_CAP 8192
#define IMGMAX 639.0f      // IMG_W - TO_REMOVE
#define BBOX_CLIP 4.135166556742356f  // log(1000/16)

// ---- orderable key for float (descending sort by value == descending by key) ----
__device__ __forceinline__ unsigned int f2key(float x) {
    unsigned int u = __float_as_uint(x);
    return (u & 0x80000000u) ? ~u : (u | 0x80000000u);
}
__device__ __forceinline__ float key2f(unsigned int k) {
    unsigned int u = (k & 0x80000000u) ? (k & 0x7FFFFFFFu) : ~k;
    return __uint_as_float(u);
}

// =====================================================================
// K1: per-image top-K threshold via 2-level 12-bit histogram, then compact
// grid: 16 blocks x 1024 threads (one block per image)
// =====================================================================
__global__ __launch_bounds__(1024) void k_select(
        const float* __restrict__ obj,
        unsigned int* __restrict__ cand_key,
        unsigned int* __restrict__ cand_idx,
        unsigned int* __restrict__ cand_cnt) {
    const int n = blockIdx.x;
    const float* o = obj + (size_t)n * P_;
    __shared__ unsigned int hist[4096];
    __shared__ unsigned int ssum[64];
    __shared__ unsigned int s_b1, s_cb, s_thr, s_cnt;
    const int tid = threadIdx.x;

    // ---- pass A: histogram of top 12 key bits ----
    for (int t = tid; t < 4096; t += 1024) hist[t] = 0;
    __syncthreads();
    for (int q = tid; q < P_; q += 1024) {
        unsigned int k = f2key(o[q]);
        atomicAdd(&hist[k >> 20], 1u);
    }
    __syncthreads();
    if (tid < 64) {
        unsigned int s = 0;
        for (int m = 0; m < 64; ++m) s += hist[tid * 64 + m];
        ssum[tid] = s;
    }
    __syncthreads();
    if (tid == 0) {
        unsigned int acc = 0; int b1 = 0;
        for (int sb = 63; sb >= 0; --sb) {
            if (acc + ssum[sb] >= (unsigned)K1) {
                for (int b = sb * 64 + 63; b >= sb * 64; --b) {
                    if (acc + hist[b] >= (unsigned)K1) { b1 = b; break; }
                    acc += hist[b];
                }
                break;
            }
            acc += ssum[sb];
        }
        s_b1 = (unsigned)b1;   // threshold bucket (top 12 bits)
        s_cb = acc;            // count of keys strictly above bucket b1
    }
    __syncthreads();
    const unsigned int b1 = s_b1, cb = s_cb;

    // ---- pass B: refine inside bucket b1 with next 12 bits ----
    for (int t = tid; t < 4096; t += 1024) hist[t] = 0;
    __syncthreads();
    for (int q = tid; q < P_; q += 1024) {
        unsigned int k = f2key(o[q]);
        if ((k >> 20) == b1) atomicAdd(&hist[(k >> 8) & 0xFFFu], 1u);
    }
    __syncthreads();
    if (tid < 64) {
        unsigned int s = 0;
        for (int m = 0; m < 64; ++m) s += hist[tid * 64 + m];
        ssum[tid] = s;
    }
    __syncthreads();
    if (tid == 0) {
        const unsigned int R = (unsigned)K1 - cb;  // remaining rank inside bucket b1
        unsigned int acc = 0; int b2 = 0;
        for (int sb = 63; sb >= 0; --sb) {
            if (acc + ssum[sb] >= R) {
                for (int b = sb * 64 + 63; b >= sb * 64; --b) {
                    if (acc + hist[b] >= R) { b2 = b; break; }
                    acc += hist[b];
                }
                break;
            }
            acc += ssum[sb];
        }
        s_thr = (b1 << 20) | ((unsigned int)b2 << 8);
        s_cnt = 0;
    }
    __syncthreads();
    const unsigned int T = s_thr;

    // ---- pass C: compact all keys >= T ----
    for (int q = tid; q < P_; q += 1024) {
        unsigned int k = f2key(o[q]);
        if (k >= T) {
            unsigned int pos = atomicAdd(&s_cnt, 1u);
            if (pos < CAND_CAP) {
                cand_key[(size_t)n * CAND_CAP + pos] = k;
                // memory order q = a*HW + hw  ->  flattened p = hw*A + a
                cand_idx[(size_t)n * CAND_CAP + pos] =
                    (unsigned int)((q % HW_) * A_ + (q / HW_));
            }
        }
    }
    __syncthreads();
    if (tid == 0) cand_cnt[n] = (s_cnt < CAND_CAP) ? s_cnt : CAND_CAP;
}

// =====================================================================
// K2: per-image bitonic sort of 8192 candidates (desc key, asc idx),
// emit sorted top-4096 indices + sigmoid scores.
// grid: 16 blocks x 1024 threads
// =====================================================================
__global__ __launch_bounds__(1024) void k_sort(
        const unsigned int* __restrict__ cand_key,
        const unsigned int* __restrict__ cand_idx,
        const unsigned int* __restrict__ cand_cnt,
        unsigned int* __restrict__ sidx,
        float* __restrict__ sscore) {
    const int n = blockIdx.x;
    __shared__ unsigned int kk[CAND_CAP];
    __shared__ unsigned int ii[CAND_CAP];
    const int tid = threadIdx.x;
    const unsigned int cnt = cand_cnt[n];

    for (int t = tid; t < CAND_CAP; t += 1024) {
        if (t < (int)cnt) {
            kk[t] = cand_key[(size_t)n * CAND_CAP + t];
            ii[t] = cand_idx[(size_t)n * CAND_CAP + t];
        } else {
            kk[t] = 0u;            // below every real key
            ii[t] = 0x7FFFFFFFu;
        }
    }
    __syncthreads();

    for (int k = 2; k <= CAND_CAP; k <<= 1) {
        for (int j = k >> 1; j > 0; j >>= 1) {
            for (int t = tid; t < CAND_CAP; t += 1024) {
                int ixj = t ^ j;
                if (ixj > t) {
                    unsigned int ka = kk[t],  kb = kk[ixj];
                    unsigned int ia = ii[t],  ib = ii[ixj];
                    bool asc = ((t & k) == 0);
                    // desired order: key desc, idx asc.  pre(x,y) = x before y.
                    bool pre_b_a = (kb > ka) || (kb == ka && ib < ia);
                    bool pre_a_b = (ka > kb) || (ka == kb && ia < ib);
                    bool doSwap = asc ? pre_b_a : pre_a_b;
                    if (doSwap) {
                        kk[t] = kb; kk[ixj] = ka;
                        ii[t] = ib; ii[ixj] = ia;
                    }
                }
            }
            __syncthreads();
        }
    }

    for (int t = tid; t < K1; t += 1024) {
        sidx[(size_t)n * K1 + t] = ii[t];
        float x = key2f(kk[t]);
        sscore[(size_t)n * K1 + t] = 1.0f / (1.0f + expf(-x));
    }
}

// =====================================================================
// K3: gather reg/anchors/cls at sorted indices; decode + clip; class argmax.
// one thread per (image, rank). grid: 256 blocks x 256 threads = 65536
// =====================================================================
__global__ __launch_bounds__(256) void k_decode(
        const unsigned int* __restrict__ sidx,
        const float* __restrict__ anchors,
        const float* __restrict__ reg,
        const float* __restrict__ cls,
        float* __restrict__ bx1, float* __restrict__ by1,
        float* __restrict__ bx2, float* __restrict__ by2,
        float* __restrict__ blab) {
#pragma clang fp contract(off)
    const int gid = blockIdx.x * 256 + threadIdx.x;
    if (gid >= NIMG * K1) return;
    const int n = gid >> 12;           // / 4096
    const unsigned int p = sidx[gid];
    const int a = (int)(p % 3u);
    const int hw = (int)(p / 3u);

    // box_regression[n, a*4+k, h, w], stride HW between k's
    const float* rb = reg + ((size_t)n * 12 + a * 4) * HW_ + hw;
    float dx = rb[0];
    float dy = rb[HW_];
    float dw = rb[2 * HW_];
    float dh = rb[3 * HW_];

    const float* an = anchors + ((size_t)n * P_ + p) * 4;
    float a0 = an[0], a1 = an[1], a2 = an[2], a3 = an[3];

    // BoxCoder.decode, op-for-op (no fma contraction)
    float w  = a2 - a0 + 1.0f;
    float h  = a3 - a1 + 1.0f;
    float cx = a0 + 0.5f * w;
    float cy = a1 + 0.5f * h;
    float dwc = fminf(dw, BBOX_CLIP);
    float dhc = fminf(dh, BBOX_CLIP);
    float pcx = dx * w + cx;
    float pcy = dy * h + cy;
    float pw  = expf(dwc) * w;
    float ph  = expf(dhc) * h;
    float x1 = pcx - 0.5f * pw;
    float y1 = pcy - 0.5f * ph;
    float x2 = pcx + 0.5f * pw - 1.0f;
    float y2 = pcy + 0.5f * ph - 1.0f;
    // clip_to_image
    x1 = fminf(fmaxf(x1, 0.0f), IMGMAX);
    y1 = fminf(fmaxf(y1, 0.0f), IMGMAX);
    x2 = fminf(fmaxf(x2, 0.0f), IMGMAX);
    y2 = fminf(fmaxf(y2, 0.0f), IMGMAX);

    bx1[gid] = x1; by1[gid] = y1; bx2[gid] = x2; by2[gid] = y2;

    // class argmax (first-max tie-break, matches jnp.argmax)
    const float* cb = cls + ((size_t)n * 240 + a * 80) * HW_ + hw;
    float best = cb[0];
    int lab = 0;
    for (int c = 1; c < C_; ++c) {
        float v = cb[(size_t)c * HW_];
        if (v > best) { best = v; lab = c; }
    }
    blab[gid] = (float)(lab + 1);
}

// =====================================================================
// K4: per-image greedy NMS (boxes already in descending score order),
// then write the [300, 6] output rows.
// grid: 16 blocks x 1024 threads
// =====================================================================
__global__ __launch_bounds__(1024) void k_nms(
        const float* __restrict__ gx1, const float* __restrict__ gy1,
        const float* __restrict__ gx2, const float* __restrict__ gy2,
        const float* __restrict__ gsc, const float* __restrict__ glab,
        float* __restrict__ out) {
#pragma clang fp contract(off)
    const int n = blockIdx.x;
    __shared__ float sx1[K1], sy1[K1], sx2[K1], sy2[K1];
    __shared__ unsigned char srem[K1];
    __shared__ int skept[K2];
    __shared__ int s_sel, s_cursor;
    const int tid = threadIdx.x;

    for (int t = tid; t < K1; t += 1024) {
        sx1[t] = gx1[(size_t)n * K1 + t];
        sy1[t] = gy1[(size_t)n * K1 + t];
        sx2[t] = gx2[(size_t)n * K1 + t];
        sy2[t] = gy2[(size_t)n * K1 + t];
        srem[t] = 0;
    }
    for (int t = tid; t < K2; t += 1024) skept[t] = -1;
    if (tid == 0) s_cursor = 0;
    __syncthreads();

    for (int iter = 0; iter < K2; ++iter) {
        if (tid == 0) {
            int c = s_cursor;
            while (c < K1 && srem[c]) ++c;
            if (c < K1) { skept[iter] = c; s_sel = c; s_cursor = c + 1; }
            else s_sel = -1;
        }
        __syncthreads();
        const int sel = s_sel;
        if (sel < 0) break;  // uniform
        const float qx1 = sx1[sel], qy1 = sy1[sel];
        const float qx2 = sx2[sel], qy2 = sy2[sel];
        const float qa = (qx2 - qx1 + 1.0f) * (qy2 - qy1 + 1.0f);
        for (int t = tid; t < K1; t += 1024) {
            if (!srem[t]) {
                float iw = fminf(qx2, sx2[t]) - fmaxf(qx1, sx1[t]) + 1.0f;
                float ih = fminf(qy2, sy2[t]) - fmaxf(qy1, sy1[t]) + 1.0f;
                iw = fmaxf(iw, 0.0f);
                ih = fmaxf(ih, 0.0f);
                float inter = iw * ih;
                float ta = (sx2[t] - sx1[t] + 1.0f) * (sy2[t] - sy1[t] + 1.0f);
                float iou = inter / (qa + ta - inter);   // (qa+ta)-inter, exact div
                if (iou > 0.5f) srem[t] = 1;
            }
        }
        __syncthreads();
    }
    __syncthreads();

    // epilogue: write [n, 300, 6]
    for (int k = tid; k < K2; k += 1024) {
        int sel = skept[k];
        float o0 = 0.f, o1 = 0.f, o2 = 0.f, o3 = 0.f, o4 = 0.f, o5 = 0.f;
        if (sel >= 0) {
            o0 = sx1[sel]; o1 = sy1[sel]; o2 = sx2[sel]; o3 = sy2[sel];
            o4 = gsc[(size_t)n * K1 + sel];
            o5 = glab[(size_t)n * K1 + sel];
        }
        float* op = out + ((size_t)n * K2 + k) * 6;
        op[0] = o0; op[1] = o1; op[2] = o2;
        op[3] = o3; op[4] = o4; op[5] = o5;
    }
}

// =====================================================================
extern "C" void kernel_launch(void* const* d_in, const int* in_sizes, int n_in,
                              void* d_out, int out_size, void* d_ws, size_t ws_size,
                              hipStream_t stream) {
    (void)in_sizes; (void)n_in; (void)out_size; (void)ws_size;
    const float* anchors    = (const float*)d_in[0];
    const float* objectness = (const float*)d_in[1];
    const float* box_reg    = (const float*)d_in[2];
    const float* cls        = (const float*)d_in[3];
    float* out = (float*)d_out;

    char* ws = (char*)d_ws;
    size_t off = 0;
    unsigned int* cand_key = (unsigned int*)(ws + off); off += (size_t)NIMG * CAND_CAP * 4;
    unsigned int* cand_idx = (unsigned int*)(ws + off); off += (size_t)NIMG * CAND_CAP * 4;
    unsigned int* cand_cnt = (unsigned int*)(ws + off); off += 256;
    unsigned int* sidx     = (unsigned int*)(ws + off); off += (size_t)NIMG * K1 * 4;
    float* sscore = (float*)(ws + off); off += (size_t)NIMG * K1 * 4;
    float* blab   = (float*)(ws + off); off += (size_t)NIMG * K1 * 4;
    float* bx1    = (float*)(ws + off); off += (size_t)NIMG * K1 * 4;
    float* by1    = (float*)(ws + off); off += (size_t)NIMG * K1 * 4;
    float* bx2    = (float*)(ws + off); off += (size_t)NIMG * K1 * 4;
    float* by2    = (float*)(ws + off); off += (size_t)NIMG * K1 * 4;
    // total ~2.6 MB of workspace

    k_select<<<NIMG, 1024, 0, stream>>>(objectness, cand_key, cand_idx, cand_cnt);
    k_sort  <<<NIMG, 1024, 0, stream>>>(cand_key, cand_idx, cand_cnt, sidx, sscore);
    k_decode<<<(NIMG * K1) / 256, 256, 0, stream>>>(sidx, anchors, box_reg, cls,
                                                    bx1, by1, bx2, by2, blab);
    k_nms   <<<NIMG, 1024, 0, stream>>>(bx1, by1, bx2, by2, sscore, blab, out);
}